// Round 11
// baseline (455.946 us; speedup 1.0000x reference)
//
#include <hip/hip_runtime.h>
#include <hip/hip_bf16.h>
#include <math.h>

typedef short short8_t __attribute__((ext_vector_type(8)));
typedef float floatx4  __attribute__((ext_vector_type(4)));
typedef float floatx2  __attribute__((ext_vector_type(2)));
typedef unsigned int uint;

// ---------------- bf16 helpers (RNE) ----------------------------------------

__device__ inline unsigned short f2b(float f) {
    uint u = __float_as_uint(f);
    u += 0x7fff + ((u >> 16) & 1);
    return (unsigned short)(u >> 16);
}
__device__ inline uint pack2(float a, float b) {
    return (uint)f2b(a) | ((uint)f2b(b) << 16);
}
__device__ inline float blo(uint v) { return __uint_as_float(v << 16); }
__device__ inline float bhi(uint v) { return __uint_as_float(v & 0xffff0000u); }

// ---------------- fp8 (e4m3) helpers ------------------------------------------

__device__ inline uint enc4_fp8(float f0, float f1, float f2, float f3) {
    uint v = __builtin_amdgcn_cvt_pk_fp8_f32(f0, f1, 0, false);
    v = __builtin_amdgcn_cvt_pk_fp8_f32(f2, f3, v, true);
    return v;
}
__device__ inline unsigned char enc1_fp8(float f) {
    return (unsigned char)(__builtin_amdgcn_cvt_pk_fp8_f32(f, f, 0, false) & 0xff);
}

// ---------------- phase A mega-kernel -----------------------------------------
// R10 lesson: the atomic count pass is pinned at ~43us by the device-atomic
// pipe (~23 G atomics/s) regardless of ILP depth; it uses <1% VALU and 11%
// HBM. So co-schedule the independent conversion work in the same launch:
// grid = [count_pos | cvt_x | cvt_w | graph_bounds], split by blockIdx.

__global__ __launch_bounds__(256) void k_phase_a(
    // count_pos
    const int* __restrict__ dst, int* __restrict__ deg, int* __restrict__ epos, int E,
    // cvt_x
    const float* __restrict__ x, unsigned short* __restrict__ xb,
    unsigned char* __restrict__ xf8, int nX,
    // cvt_w
    const float* __restrict__ Wl1, const float* __restrict__ Wr1,
    const float* __restrict__ Wl2, const float* __restrict__ Wr2,
    unsigned short* __restrict__ wbuf,
    // graph bounds
    const int* __restrict__ batch, int* __restrict__ gstart, int N, int G,
    // block ranges
    int bCount, int bCvtX, int bCvtW) {
    int b = blockIdx.x;
    if (b < bCount) {
        int e = (b * 256 + threadIdx.x) * 4;
        if (e + 3 < E) {
            int4 d4 = *(const int4*)(dst + e);
            int4 p;
            p.x = atomicAdd(&deg[d4.x], 1);
            p.y = atomicAdd(&deg[d4.y], 1);
            p.z = atomicAdd(&deg[d4.z], 1);
            p.w = atomicAdd(&deg[d4.w], 1);
            *(int4*)(epos + e) = p;
        } else {
            for (int k = e; k < E; ++k) epos[k] = atomicAdd(&deg[dst[k]], 1);
        }
    } else if (b < bCount + bCvtX) {
        int i = ((b - bCount) * 256 + threadIdx.x) * 8;
        if (i < nX) {
            float4 v0 = *(const float4*)(x + i);
            float4 v1 = *(const float4*)(x + i + 4);
            uint4 ob;
            ob.x = pack2(v0.x, v0.y);
            ob.y = pack2(v0.z, v0.w);
            ob.z = pack2(v1.x, v1.y);
            ob.w = pack2(v1.z, v1.w);
            *(uint4*)(xb + i) = ob;
            uint2 of;
            of.x = enc4_fp8(v0.x, v0.y, v0.z, v0.w);
            of.y = enc4_fp8(v1.x, v1.y, v1.z, v1.w);
            *(uint2*)(xf8 + i) = of;
        }
    } else if (b < bCount + bCvtX + bCvtW) {
        int i = (b - bCount - bCvtX) * 256 + threadIdx.x;
        if (i < 49152) {
            float v;
            if (i < 8192)       v = Wl1[i];
            else if (i < 16384) v = Wr1[i - 8192];
            else if (i < 32768) v = Wl2[i - 16384];
            else                v = Wr2[i - 32768];
            wbuf[i] = f2b(v);
        }
    } else {
        for (int g = threadIdx.x; g <= G; g += 256) {
            if (g == G) { gstart[G] = N; continue; }
            int lo = 0, hi = N;
            while (lo < hi) {
                int mid = (lo + hi) >> 1;
                if (batch[mid] < g) lo = mid + 1; else hi = mid;
            }
            gstart[g] = lo;
        }
    }
}

// ---------------- scan (3-phase) ----------------------------------------------

__global__ void k_block_sum(const int* __restrict__ deg, int* __restrict__ bsum, int n) {
    __shared__ int red[256];
    int i = blockIdx.x * 256 + threadIdx.x;
    red[threadIdx.x] = (i < n) ? deg[i] : 0;
    __syncthreads();
#pragma unroll
    for (int off = 128; off > 0; off >>= 1) {
        if (threadIdx.x < off) red[threadIdx.x] += red[threadIdx.x + off];
        __syncthreads();
    }
    if (threadIdx.x == 0) bsum[blockIdx.x] = red[0];
}

__global__ void k_scan_bsum(int* __restrict__ bsum, int nb) {
    __shared__ int s[512];
    int t = threadIdx.x;
    int v = (t < nb) ? bsum[t] : 0;
    s[t] = v;
    __syncthreads();
#pragma unroll
    for (int off = 1; off < 512; off <<= 1) {
        int u = (t >= off) ? s[t - off] : 0;
        __syncthreads();
        s[t] += u;
        __syncthreads();
    }
    if (t < nb) bsum[t] = s[t] - v;
}

__global__ void k_scan_final(const int* __restrict__ deg, const int* __restrict__ bsum,
                             int* __restrict__ row_start, int n) {
    __shared__ int s[256];
    int i = blockIdx.x * 256 + threadIdx.x;
    int v = (i < n) ? deg[i] : 0;
    s[threadIdx.x] = v;
    __syncthreads();
#pragma unroll
    for (int off = 1; off < 256; off <<= 1) {
        int u = (threadIdx.x >= off) ? s[threadIdx.x - off] : 0;
        __syncthreads();
        s[threadIdx.x] += u;
        __syncthreads();
    }
    int excl = s[threadIdx.x] - v + bsum[blockIdx.x];
    if (i < n) row_start[i] = excl;
    if (i == n - 1) row_start[n] = excl + v;
}

// pass 2: atomic-free placement, 8 edges/thread. Packed CSR (4MB, L2-resident;
// R9 lesson: strided buckets caused 16x write amplification).
__global__ void k_place(const int* __restrict__ src, const int* __restrict__ dst,
                        const int* __restrict__ row_start, const int* __restrict__ epos,
                        int* __restrict__ csr_src, int E) {
    int e = (blockIdx.x * blockDim.x + threadIdx.x) * 8;
    if (e + 7 < E) {
        int4 d0 = *(const int4*)(dst + e);
        int4 d1 = *(const int4*)(dst + e + 4);
        int4 p0 = *(const int4*)(epos + e);
        int4 p1 = *(const int4*)(epos + e + 4);
        int4 s0 = *(const int4*)(src + e);
        int4 s1 = *(const int4*)(src + e + 4);
        int r0 = row_start[d0.x];
        int r1 = row_start[d0.y];
        int r2 = row_start[d0.z];
        int r3 = row_start[d0.w];
        int r4 = row_start[d1.x];
        int r5 = row_start[d1.y];
        int r6 = row_start[d1.z];
        int r7 = row_start[d1.w];
        csr_src[r0 + p0.x] = s0.x;
        csr_src[r1 + p0.y] = s0.y;
        csr_src[r2 + p0.z] = s0.z;
        csr_src[r3 + p0.w] = s0.w;
        csr_src[r4 + p1.x] = s1.x;
        csr_src[r5 + p1.y] = s1.y;
        csr_src[r6 + p1.z] = s1.z;
        csr_src[r7 + p1.w] = s1.w;
    } else {
        for (int k = e; k < E; ++k) csr_src[row_start[dst[k]] + epos[k]] = src[k];
    }
}

// ---------------- fused layer: gather(LDS) + MFMA linear ----------------------
// out = relu(mean_agg(feat)@Wl.T + bl + xin@Wr.T), feat gathered in fp8,
// agg kept in LDS (padded stride K+8 shorts -> bank starts cover all 32
// banks, only free 2-way aliasing). F8OUT also emits fp8 copy of out.

#define ACCF8(v)                                                        \
    { floatx2 f = __builtin_amdgcn_cvt_pk_f32_fp8((v).x, false);        \
      a[0] += f[0]; a[1] += f[1];                                       \
      f = __builtin_amdgcn_cvt_pk_f32_fp8((v).x, true);                 \
      a[2] += f[0]; a[3] += f[1];                                       \
      f = __builtin_amdgcn_cvt_pk_f32_fp8((v).y, false);                \
      a[4] += f[0]; a[5] += f[1];                                       \
      f = __builtin_amdgcn_cvt_pk_f32_fp8((v).y, true);                 \
      a[6] += f[0]; a[7] += f[1]; }

template <int K, bool F8OUT>
__global__ __launch_bounds__(256) void k_layer(
    const unsigned char* __restrict__ featf8,
    const unsigned short* __restrict__ xinA,
    const int* __restrict__ row_start, const int* __restrict__ csr_src,
    const unsigned short* __restrict__ Wlb,  const float* __restrict__ bl,
    const unsigned short* __restrict__ Wrb,  unsigned short* __restrict__ out,
    unsigned char* __restrict__ outf8, int n_nodes) {
    constexpr int PK  = K + 8;         // padded LDS row stride (shorts)
    constexpr int NCH = (2 * K) / 32;
    __shared__ __align__(16) short aggL[128 * PK];
    __shared__ __align__(16) short As[128 * 32];

    int tid  = threadIdx.x;
    int lane = tid & 63;
    int wave = tid >> 6;
    int quad = lane >> 4;
    int lr   = lane & 15;
    int node0 = blockIdx.x * 128;

    // ---- phase 1: gather 32 nodes per wave into aggL (fp8 rows, fp32 acc) ----
    {
        int grp, lp, stride;
        if (K == 64) { grp = lane >> 3; lp = lane & 7;  stride = 8; }
        else         { grp = lane >> 4; lp = lane & 15; stride = 4; }
        for (int ii = 0; ii < 32; ++ii) {
            int nl = wave * 32 + ii;
            int node = node0 + nl;
            if (node < n_nodes) {
                float a[8];
#pragma unroll
                for (int q = 0; q < 8; ++q) a[q] = 0.f;
                int s = row_start[node];
                int e = row_start[node + 1];
                int i = s + grp;
                for (; i + stride < e; i += 2 * stride) {
                    int u0 = csr_src[i];
                    int u1 = csr_src[i + stride];
                    uint2 v0 = *(const uint2*)(featf8 + (size_t)u0 * K + lp * 8);
                    uint2 v1 = *(const uint2*)(featf8 + (size_t)u1 * K + lp * 8);
                    ACCF8(v0);
                    ACCF8(v1);
                }
                if (i < e) {
                    int u0 = csr_src[i];
                    uint2 v0 = *(const uint2*)(featf8 + (size_t)u0 * K + lp * 8);
                    ACCF8(v0);
                }
                if (K == 64) {
#pragma unroll
                    for (int q = 0; q < 8; ++q) {
                        a[q] += __shfl_xor(a[q], 8);
                        a[q] += __shfl_xor(a[q], 16);
                        a[q] += __shfl_xor(a[q], 32);
                    }
                } else {
#pragma unroll
                    for (int q = 0; q < 8; ++q) {
                        a[q] += __shfl_xor(a[q], 16);
                        a[q] += __shfl_xor(a[q], 32);
                    }
                }
                if (grp == 0) {
                    int d = e - s;
                    float scale = (d > 0) ? (1.f / (float)d) : 1.f;
                    uint4 o;
                    o.x = pack2(a[0] * scale, a[1] * scale);
                    o.y = pack2(a[2] * scale, a[3] * scale);
                    o.z = pack2(a[4] * scale, a[5] * scale);
                    o.w = pack2(a[6] * scale, a[7] * scale);
                    *(uint4*)(&aggL[nl * PK + lp * 8]) = o;
                }
            } else if (grp == 0) {
                *(uint4*)(&aggL[nl * PK + lp * 8]) = make_uint4(0, 0, 0, 0);
            }
        }
    }
    __syncthreads();

    // ---- phase 2: MFMA. agg chunks read straight from aggL; xin chunks staged.
    floatx4 acc[8][2];
#pragma unroll
    for (int mi = 0; mi < 8; ++mi)
#pragma unroll
        for (int ni = 0; ni < 2; ++ni)
            acc[mi][ni] = (floatx4){0.f, 0.f, 0.f, 0.f};

    int srow = tid >> 2;
    int sslot = tid & 3;

#pragma unroll
    for (int c = 0; c < NCH; ++c) {
        const bool isAgg = (c < K / 32);
        int kb = isAgg ? c * 32 : c * 32 - K;
        const unsigned short* srcW = isAgg ? Wlb : Wrb;

        if (!isAgg) {
            __syncthreads();
            {
                int n1 = node0 + srow;       if (n1 >= n_nodes) n1 = n_nodes - 1;
                int n2 = node0 + srow + 64;  if (n2 >= n_nodes) n2 = n_nodes - 1;
                uint4 v1 = *(const uint4*)(xinA + (size_t)n1 * K + kb + sslot * 8);
                uint4 v2 = *(const uint4*)(xinA + (size_t)n2 * K + kb + sslot * 8);
                *(uint4*)(&As[srow * 32 + sslot * 8]) = v1;
                *(uint4*)(&As[(srow + 64) * 32 + sslot * 8]) = v2;
            }
            __syncthreads();
        }

        short8_t bfrag[2];
#pragma unroll
        for (int ni = 0; ni < 2; ++ni) {
            int j = wave * 32 + ni * 16 + lr;
            bfrag[ni] = *(const short8_t*)(srcW + (size_t)j * K + kb + quad * 8);
        }
#pragma unroll
        for (int mi = 0; mi < 8; ++mi) {
            short8_t af;
            if (isAgg)
                af = *(const short8_t*)(&aggL[(mi * 16 + lr) * PK + kb + quad * 8]);
            else
                af = *(const short8_t*)(&As[(mi * 16 + lr) * 32 + quad * 8]);
            acc[mi][0] = __builtin_amdgcn_mfma_f32_16x16x32_bf16(af, bfrag[0], acc[mi][0], 0, 0, 0);
            acc[mi][1] = __builtin_amdgcn_mfma_f32_16x16x32_bf16(af, bfrag[1], acc[mi][1], 0, 0, 0);
        }
    }

    float b0 = bl[wave * 32 + lr];
    float b1 = bl[wave * 32 + 16 + lr];
    int j0 = wave * 32 + lr;
#pragma unroll
    for (int mi = 0; mi < 8; ++mi) {
#pragma unroll
        for (int r = 0; r < 4; ++r) {
            int node = node0 + mi * 16 + quad * 4 + r;
            if (node < n_nodes) {
                float v0 = fmaxf(acc[mi][0][r] + b0, 0.f);
                float v1 = fmaxf(acc[mi][1][r] + b1, 0.f);
                out[(size_t)node * 128 + j0]      = f2b(v0);
                out[(size_t)node * 128 + j0 + 16] = f2b(v1);
                if (F8OUT) {
                    outf8[(size_t)node * 128 + j0]      = enc1_fp8(v0);
                    outf8[(size_t)node * 128 + j0 + 16] = enc1_fp8(v1);
                }
            }
        }
    }
}

// ---------------- fused pool + head -------------------------------------------

__global__ __launch_bounds__(256) void k_pool_head(const unsigned short* __restrict__ h2b,
                                                   const int* __restrict__ gstart,
                                                   const float* __restrict__ Wout,
                                                   const float* __restrict__ bout,
                                                   float* __restrict__ out) {
    int g = blockIdx.x;
    int s = gstart[g], e = gstart[g + 1];
    int lane = threadIdx.x & 63;
    int wave = threadIdx.x >> 6;
    float ax = 0.f, ay = 0.f;
    for (int n = s + wave; n < e; n += 4) {
        uint v = ((const uint*)(h2b + (size_t)n * 128))[lane];
        ax += blo(v);
        ay += bhi(v);
    }
    __shared__ float2 red[4][64];
    red[wave][lane] = make_float2(ax, ay);
    __syncthreads();
    if (wave == 0) {
        float2 a = red[0][lane], b = red[1][lane], c = red[2][lane], d = red[3][lane];
        float cnt = (float)(e - s);
        float inv = (cnt > 0.f) ? (1.f / cnt) : 1.f;
        float px = (a.x + b.x + c.x + d.x) * inv;
        float py = (a.y + b.y + c.y + d.y) * inv;
        float2 w0 = ((const float2*)(Wout))[lane];
        float2 w1 = ((const float2*)(Wout + 128))[lane];
        float d0 = px * w0.x + py * w0.y;
        float d1 = px * w1.x + py * w1.y;
#pragma unroll
        for (int m = 32; m > 0; m >>= 1) {
            d0 += __shfl_xor(d0, m);
            d1 += __shfl_xor(d1, m);
        }
        if (lane == 0) {
            float l0 = d0 + bout[0];
            float l1 = d1 + bout[1];
            float mx = fmaxf(l0, l1);
            float lse = mx + logf(expf(l0 - mx) + expf(l1 - mx));
            out[g * 2 + 0] = l0 - lse;
            out[g * 2 + 1] = l1 - lse;
        }
    }
}

// ---------------- launch -----------------------------------------------------

static inline size_t alignUp(size_t x, size_t a) { return (x + a - 1) & ~(a - 1); }

extern "C" void kernel_launch(void* const* d_in, const int* in_sizes, int n_in,
                              void* d_out, int out_size, void* d_ws, size_t ws_size,
                              hipStream_t stream) {
    const float* x    = (const float*)d_in[0];
    const int*   ei   = (const int*)d_in[1];
    const int*   batch= (const int*)d_in[2];
    const float* Wl1  = (const float*)d_in[3];
    const float* bl1  = (const float*)d_in[4];
    const float* Wr1  = (const float*)d_in[5];
    const float* Wl2  = (const float*)d_in[6];
    const float* bl2  = (const float*)d_in[7];
    const float* Wr2  = (const float*)d_in[8];
    const float* Wout = (const float*)d_in[9];
    const float* bout = (const float*)d_in[10];
    float* out = (float*)d_out;

    const int N = in_sizes[0] / 64;   // 100000
    const int E = in_sizes[1] / 2;    // 1000000
    const int G = out_size / 2;       // 256

    const int* src = ei;
    const int* dst = ei + E;

    const int nScanBlocks = (N + 255) / 256;

    // workspace layout
    char* ws = (char*)d_ws;
    size_t off = 0;
    int*   deg       = (int*)(ws + off); off = alignUp(off + (size_t)N * 4, 256);
    int*   row_start = (int*)(ws + off); off = alignUp(off + (size_t)(N + 1) * 4, 256);
    int*   epos      = (int*)(ws + off); off = alignUp(off + (size_t)E * 4, 256);
    int*   csr_src   = (int*)(ws + off); off = alignUp(off + (size_t)E * 4, 256);
    int*   bsum      = (int*)(ws + off); off = alignUp(off + (size_t)512 * 4, 256);
    int*   gstart    = (int*)(ws + off); off = alignUp(off + (size_t)(G + 1) * 4, 256);
    unsigned short* xb   = (unsigned short*)(ws + off); off = alignUp(off + (size_t)N * 64 * 2, 256);
    unsigned char*  xf8  = (unsigned char*)(ws + off);  off = alignUp(off + (size_t)N * 64, 256);
    unsigned short* wbuf = (unsigned short*)(ws + off); off = alignUp(off + (size_t)49152 * 2, 256);
    unsigned short* h1   = (unsigned short*)(ws + off); off = alignUp(off + (size_t)N * 128 * 2, 256);
    unsigned char*  h1f8 = (unsigned char*)(ws + off);  off = alignUp(off + (size_t)N * 128, 256);
    unsigned short* h2b  = (unsigned short*)(ws + off); off = alignUp(off + (size_t)N * 128 * 2, 256);
    (void)ws_size;

    unsigned short* Wl1b = wbuf;
    unsigned short* Wr1b = wbuf + 8192;
    unsigned short* Wl2b = wbuf + 16384;
    unsigned short* Wr2b = wbuf + 32768;

    // zero deg
    hipMemsetAsync(deg, 0, (size_t)N * 4, stream);

    // phase A: count_pos + cvt_x + cvt_w + graph_bounds in one launch
    const int bCount = (E / 4 + 255) / 256;          // 977
    const int bCvtX  = (N * 64 / 8 + 255) / 256;     // 3125
    const int bCvtW  = 192;
    k_phase_a<<<bCount + bCvtX + bCvtW + 1, 256, 0, stream>>>(
        dst, deg, epos, E,
        x, xb, xf8, N * 64,
        Wl1, Wr1, Wl2, Wr2, wbuf,
        batch, gstart, N, G,
        bCount, bCvtX, bCvtW);

    // scan + placement
    k_block_sum<<<nScanBlocks, 256, 0, stream>>>(deg, bsum, N);
    k_scan_bsum<<<1, 512, 0, stream>>>(bsum, nScanBlocks);
    k_scan_final<<<nScanBlocks, 256, 0, stream>>>(deg, bsum, row_start, N);
    k_place<<<(E / 8 + 255) / 256, 256, 0, stream>>>(src, dst, row_start, epos, csr_src, E);

    // layer 1 (fused gather+linear): emits h1 (bf16) + h1f8 (fp8)
    k_layer<64, true><<<(N + 127) / 128, 256, 0, stream>>>(
        xf8, xb, row_start, csr_src, Wl1b, bl1, Wr1b, h1, h1f8, N);

    // layer 2 (fused): emits h2b (bf16)
    k_layer<128, false><<<(N + 127) / 128, 256, 0, stream>>>(
        h1f8, h1, row_start, csr_src, Wl2b, bl2, Wr2b, h2b, (unsigned char*)nullptr, N);

    // fused pool + head
    k_pool_head<<<G, 256, 0, stream>>>(h2b, gstart, Wout, bout, out);
}

// Round 12
// 316.358 us; speedup vs baseline: 1.4412x; 1.4412x over previous
//
#include <hip/hip_runtime.h>
#include <hip/hip_bf16.h>
#include <math.h>

typedef short short8_t __attribute__((ext_vector_type(8)));
typedef float floatx4  __attribute__((ext_vector_type(4)));
typedef float floatx2  __attribute__((ext_vector_type(2)));
typedef unsigned int uint;

// ---------------- bf16 helpers (RNE) ----------------------------------------

__device__ inline unsigned short f2b(float f) {
    uint u = __float_as_uint(f);
    u += 0x7fff + ((u >> 16) & 1);
    return (unsigned short)(u >> 16);
}
__device__ inline uint pack2(float a, float b) {
    return (uint)f2b(a) | ((uint)f2b(b) << 16);
}
__device__ inline float blo(uint v) { return __uint_as_float(v << 16); }
__device__ inline float bhi(uint v) { return __uint_as_float(v & 0xffff0000u); }

// ---------------- fp8 (e4m3) helpers ------------------------------------------

__device__ inline uint enc4_fp8(float f0, float f1, float f2, float f3) {
    uint v = __builtin_amdgcn_cvt_pk_fp8_f32(f0, f1, 0, false);
    v = __builtin_amdgcn_cvt_pk_fp8_f32(f2, f3, v, true);
    return v;
}
__device__ inline unsigned char enc1_fp8(float f) {
    return (unsigned char)(__builtin_amdgcn_cvt_pk_fp8_f32(f, f, 0, false) & 0xff);
}

// ---------------- phase A mega-kernel -----------------------------------------
// R10 lesson: atomic count pass pinned at ~43us by the device-atomic pipe
// (~23 G atomics/s) at <1% VALU / 11% HBM -> co-schedule independent
// conversion work in the same launch (count blocks first, cvt blocks ride
// the idle CUs). R11 lesson: do NOT fuse the latency-bound gather into the
// MFMA kernel (LDS+VGPR footprint kills the occupancy the gather needs);
// separate kernels co-schedule fine on their own.

__global__ __launch_bounds__(256) void k_phase_a(
    const int* __restrict__ dst, int* __restrict__ deg, int* __restrict__ epos, int E,
    const float* __restrict__ x, unsigned short* __restrict__ xb,
    unsigned char* __restrict__ xf8, int nX,
    const float* __restrict__ Wl1, const float* __restrict__ Wr1,
    const float* __restrict__ Wl2, const float* __restrict__ Wr2,
    unsigned short* __restrict__ wbuf,
    const int* __restrict__ batch, int* __restrict__ gstart, int N, int G,
    int bCount, int bCvtX, int bCvtW) {
    int b = blockIdx.x;
    if (b < bCount) {
        int e = (b * 256 + threadIdx.x) * 4;
        if (e + 3 < E) {
            int4 d4 = *(const int4*)(dst + e);
            int4 p;
            p.x = atomicAdd(&deg[d4.x], 1);
            p.y = atomicAdd(&deg[d4.y], 1);
            p.z = atomicAdd(&deg[d4.z], 1);
            p.w = atomicAdd(&deg[d4.w], 1);
            *(int4*)(epos + e) = p;
        } else {
            for (int k = e; k < E; ++k) epos[k] = atomicAdd(&deg[dst[k]], 1);
        }
    } else if (b < bCount + bCvtX) {
        int i = ((b - bCount) * 256 + threadIdx.x) * 8;
        if (i < nX) {
            float4 v0 = *(const float4*)(x + i);
            float4 v1 = *(const float4*)(x + i + 4);
            uint4 ob;
            ob.x = pack2(v0.x, v0.y);
            ob.y = pack2(v0.z, v0.w);
            ob.z = pack2(v1.x, v1.y);
            ob.w = pack2(v1.z, v1.w);
            *(uint4*)(xb + i) = ob;
            uint2 of;
            of.x = enc4_fp8(v0.x, v0.y, v0.z, v0.w);
            of.y = enc4_fp8(v1.x, v1.y, v1.z, v1.w);
            *(uint2*)(xf8 + i) = of;
        }
    } else if (b < bCount + bCvtX + bCvtW) {
        int i = (b - bCount - bCvtX) * 256 + threadIdx.x;
        if (i < 49152) {
            float v;
            if (i < 8192)       v = Wl1[i];
            else if (i < 16384) v = Wr1[i - 8192];
            else if (i < 32768) v = Wl2[i - 16384];
            else                v = Wr2[i - 32768];
            wbuf[i] = f2b(v);
        }
    } else {
        for (int g = threadIdx.x; g <= G; g += 256) {
            if (g == G) { gstart[G] = N; continue; }
            int lo = 0, hi = N;
            while (lo < hi) {
                int mid = (lo + hi) >> 1;
                if (batch[mid] < g) lo = mid + 1; else hi = mid;
            }
            gstart[g] = lo;
        }
    }
}

// ---------------- scan (3-phase) ----------------------------------------------

__global__ void k_block_sum(const int* __restrict__ deg, int* __restrict__ bsum, int n) {
    __shared__ int red[256];
    int i = blockIdx.x * 256 + threadIdx.x;
    red[threadIdx.x] = (i < n) ? deg[i] : 0;
    __syncthreads();
#pragma unroll
    for (int off = 128; off > 0; off >>= 1) {
        if (threadIdx.x < off) red[threadIdx.x] += red[threadIdx.x + off];
        __syncthreads();
    }
    if (threadIdx.x == 0) bsum[blockIdx.x] = red[0];
}

__global__ void k_scan_bsum(int* __restrict__ bsum, int nb) {
    __shared__ int s[512];
    int t = threadIdx.x;
    int v = (t < nb) ? bsum[t] : 0;
    s[t] = v;
    __syncthreads();
#pragma unroll
    for (int off = 1; off < 512; off <<= 1) {
        int u = (t >= off) ? s[t - off] : 0;
        __syncthreads();
        s[t] += u;
        __syncthreads();
    }
    if (t < nb) bsum[t] = s[t] - v;
}

__global__ void k_scan_final(const int* __restrict__ deg, const int* __restrict__ bsum,
                             int* __restrict__ row_start, int n) {
    __shared__ int s[256];
    int i = blockIdx.x * 256 + threadIdx.x;
    int v = (i < n) ? deg[i] : 0;
    s[threadIdx.x] = v;
    __syncthreads();
#pragma unroll
    for (int off = 1; off < 256; off <<= 1) {
        int u = (threadIdx.x >= off) ? s[threadIdx.x - off] : 0;
        __syncthreads();
        s[threadIdx.x] += u;
        __syncthreads();
    }
    int excl = s[threadIdx.x] - v + bsum[blockIdx.x];
    if (i < n) row_start[i] = excl;
    if (i == n - 1) row_start[n] = excl + v;
}

// atomic-free placement, 8 edges/thread. Packed CSR (4MB, L2-resident;
// R9 lesson: strided buckets caused 16x write amplification).
__global__ void k_place(const int* __restrict__ src, const int* __restrict__ dst,
                        const int* __restrict__ row_start, const int* __restrict__ epos,
                        int* __restrict__ csr_src, int E) {
    int e = (blockIdx.x * blockDim.x + threadIdx.x) * 8;
    if (e + 7 < E) {
        int4 d0 = *(const int4*)(dst + e);
        int4 d1 = *(const int4*)(dst + e + 4);
        int4 p0 = *(const int4*)(epos + e);
        int4 p1 = *(const int4*)(epos + e + 4);
        int4 s0 = *(const int4*)(src + e);
        int4 s1 = *(const int4*)(src + e + 4);
        int r0 = row_start[d0.x];
        int r1 = row_start[d0.y];
        int r2 = row_start[d0.z];
        int r3 = row_start[d0.w];
        int r4 = row_start[d1.x];
        int r5 = row_start[d1.y];
        int r6 = row_start[d1.z];
        int r7 = row_start[d1.w];
        csr_src[r0 + p0.x] = s0.x;
        csr_src[r1 + p0.y] = s0.y;
        csr_src[r2 + p0.z] = s0.z;
        csr_src[r3 + p0.w] = s0.w;
        csr_src[r4 + p1.x] = s1.x;
        csr_src[r5 + p1.y] = s1.y;
        csr_src[r6 + p1.z] = s1.z;
        csr_src[r7 + p1.w] = s1.w;
    } else {
        for (int k = e; k < E; ++k) csr_src[row_start[dst[k]] + epos[k]] = src[k];
    }
}

// ---------------- mean aggregation (fp8 in, bf16 out, fp32 accumulate) -------

#define ACCF8(v)                                                        \
    { floatx2 f = __builtin_amdgcn_cvt_pk_f32_fp8((v).x, false);        \
      a[0] += f[0]; a[1] += f[1];                                       \
      f = __builtin_amdgcn_cvt_pk_f32_fp8((v).x, true);                 \
      a[2] += f[0]; a[3] += f[1];                                       \
      f = __builtin_amdgcn_cvt_pk_f32_fp8((v).y, false);                \
      a[4] += f[0]; a[5] += f[1];                                       \
      f = __builtin_amdgcn_cvt_pk_f32_fp8((v).y, true);                 \
      a[6] += f[0]; a[7] += f[1]; }

// K=64: row = 64 B fp8. 8 edge-slots x 8 lanes x uint2; 2-deep unroll.
__global__ void k_gather1(const unsigned char* __restrict__ xf8,
                          const int* __restrict__ row_start,
                          const int* __restrict__ csr_src,
                          unsigned short* __restrict__ agg, int n_nodes) {
    int tid = threadIdx.x;
    int node = blockIdx.x * 4 + (tid >> 6);
    if (node >= n_nodes) return;
    int lane = tid & 63;
    int grp = lane >> 3;
    int lp  = lane & 7;
    int s = row_start[node];
    int e = row_start[node + 1];
    float a[8];
#pragma unroll
    for (int q = 0; q < 8; ++q) a[q] = 0.f;
    int i = s + grp;
    for (; i + 8 < e; i += 16) {
        int u0 = csr_src[i];
        int u1 = csr_src[i + 8];
        uint2 v0 = *(const uint2*)(xf8 + (size_t)u0 * 64 + lp * 8);
        uint2 v1 = *(const uint2*)(xf8 + (size_t)u1 * 64 + lp * 8);
        ACCF8(v0);
        ACCF8(v1);
    }
    if (i < e) {
        int u0 = csr_src[i];
        uint2 v0 = *(const uint2*)(xf8 + (size_t)u0 * 64 + lp * 8);
        ACCF8(v0);
    }
#pragma unroll
    for (int q = 0; q < 8; ++q) {
        a[q] += __shfl_xor(a[q], 8);
        a[q] += __shfl_xor(a[q], 16);
        a[q] += __shfl_xor(a[q], 32);
    }
    if (grp == 0) {
        int d = e - s;
        float scale = (d > 0) ? (1.f / (float)d) : 1.f;
        uint4 o;
        o.x = pack2(a[0] * scale, a[1] * scale);
        o.y = pack2(a[2] * scale, a[3] * scale);
        o.z = pack2(a[4] * scale, a[5] * scale);
        o.w = pack2(a[6] * scale, a[7] * scale);
        *(uint4*)(agg + (size_t)node * 64 + lp * 8) = o;
    }
}

// K=128: row = 128 B fp8. 4 edge-slots x 16 lanes x uint2; 2-deep unroll.
__global__ void k_gather2(const unsigned char* __restrict__ h1f8,
                          const int* __restrict__ row_start,
                          const int* __restrict__ csr_src,
                          unsigned short* __restrict__ agg, int n_nodes) {
    int tid = threadIdx.x;
    int node = blockIdx.x * 4 + (tid >> 6);
    if (node >= n_nodes) return;
    int lane = tid & 63;
    int grp = lane >> 4;
    int lp  = lane & 15;
    int s = row_start[node];
    int e = row_start[node + 1];
    float a[8];
#pragma unroll
    for (int q = 0; q < 8; ++q) a[q] = 0.f;
    int i = s + grp;
    for (; i + 4 < e; i += 8) {
        int u0 = csr_src[i];
        int u1 = csr_src[i + 4];
        uint2 v0 = *(const uint2*)(h1f8 + (size_t)u0 * 128 + lp * 8);
        uint2 v1 = *(const uint2*)(h1f8 + (size_t)u1 * 128 + lp * 8);
        ACCF8(v0);
        ACCF8(v1);
    }
    if (i < e) {
        int u0 = csr_src[i];
        uint2 v0 = *(const uint2*)(h1f8 + (size_t)u0 * 128 + lp * 8);
        ACCF8(v0);
    }
#pragma unroll
    for (int q = 0; q < 8; ++q) {
        a[q] += __shfl_xor(a[q], 16);
        a[q] += __shfl_xor(a[q], 32);
    }
    if (grp == 0) {
        int d = e - s;
        float scale = (d > 0) ? (1.f / (float)d) : 1.f;
        uint4 o;
        o.x = pack2(a[0] * scale, a[1] * scale);
        o.y = pack2(a[2] * scale, a[3] * scale);
        o.z = pack2(a[4] * scale, a[5] * scale);
        o.w = pack2(a[6] * scale, a[7] * scale);
        *(uint4*)(agg + (size_t)node * 128 + lp * 8) = o;
    }
}

// ---------------- MFMA SAGE linear: out = relu(agg@Wl.T + bl + xin@Wr.T) ----
// F8OUT: epilogue also emits fp8 copy (next layer's gather operand).

template <int K, bool F8OUT>
__global__ __launch_bounds__(256) void k_linear_mfma(
    const unsigned short* __restrict__ aggA, const unsigned short* __restrict__ xinA,
    const unsigned short* __restrict__ Wlb,  const float* __restrict__ bl,
    const unsigned short* __restrict__ Wrb,  unsigned short* __restrict__ out,
    unsigned char* __restrict__ outf8, int n_nodes) {
    constexpr int NCH = (2 * K) / 32;
    __shared__ __align__(16) short As[128 * 32];   // 8 KB

    int tid  = threadIdx.x;
    int lane = tid & 63;
    int wave = tid >> 6;
    int quad = lane >> 4;
    int lr   = lane & 15;
    int node0 = blockIdx.x * 128;

    floatx4 acc[8][2];
#pragma unroll
    for (int mi = 0; mi < 8; ++mi)
#pragma unroll
        for (int ni = 0; ni < 2; ++ni)
            acc[mi][ni] = (floatx4){0.f, 0.f, 0.f, 0.f};

    int srow = tid >> 2;
    int sslot = tid & 3;

#pragma unroll
    for (int c = 0; c < NCH; ++c) {
        const unsigned short* srcA;
        const unsigned short* srcW;
        int kb;
        if (c < K / 32) { srcA = aggA; srcW = Wlb; kb = c * 32; }
        else            { srcA = xinA; srcW = Wrb; kb = c * 32 - K; }

        __syncthreads();
        {
            int n1 = node0 + srow;       if (n1 >= n_nodes) n1 = n_nodes - 1;
            int n2 = node0 + srow + 64;  if (n2 >= n_nodes) n2 = n_nodes - 1;
            uint4 v1 = *(const uint4*)(srcA + (size_t)n1 * K + kb + sslot * 8);
            uint4 v2 = *(const uint4*)(srcA + (size_t)n2 * K + kb + sslot * 8);
            *(uint4*)(&As[srow * 32 + sslot * 8]) = v1;
            *(uint4*)(&As[(srow + 64) * 32 + sslot * 8]) = v2;
        }
        __syncthreads();

        short8_t bfrag[2];
#pragma unroll
        for (int ni = 0; ni < 2; ++ni) {
            int j = wave * 32 + ni * 16 + lr;
            bfrag[ni] = *(const short8_t*)(srcW + (size_t)j * K + kb + quad * 8);
        }
#pragma unroll
        for (int mi = 0; mi < 8; ++mi) {
            short8_t af = *(const short8_t*)(&As[(mi * 16 + lr) * 32 + quad * 8]);
            acc[mi][0] = __builtin_amdgcn_mfma_f32_16x16x32_bf16(af, bfrag[0], acc[mi][0], 0, 0, 0);
            acc[mi][1] = __builtin_amdgcn_mfma_f32_16x16x32_bf16(af, bfrag[1], acc[mi][1], 0, 0, 0);
        }
    }

    float b0 = bl[wave * 32 + lr];
    float b1 = bl[wave * 32 + 16 + lr];
    int j0 = wave * 32 + lr;
#pragma unroll
    for (int mi = 0; mi < 8; ++mi) {
#pragma unroll
        for (int r = 0; r < 4; ++r) {
            int node = node0 + mi * 16 + quad * 4 + r;
            if (node < n_nodes) {
                float v0 = fmaxf(acc[mi][0][r] + b0, 0.f);
                float v1 = fmaxf(acc[mi][1][r] + b1, 0.f);
                out[(size_t)node * 128 + j0]      = f2b(v0);
                out[(size_t)node * 128 + j0 + 16] = f2b(v1);
                if (F8OUT) {
                    outf8[(size_t)node * 128 + j0]      = enc1_fp8(v0);
                    outf8[(size_t)node * 128 + j0 + 16] = enc1_fp8(v1);
                }
            }
        }
    }
}

// ---------------- fused pool + head -------------------------------------------

__global__ __launch_bounds__(256) void k_pool_head(const unsigned short* __restrict__ h2b,
                                                   const int* __restrict__ gstart,
                                                   const float* __restrict__ Wout,
                                                   const float* __restrict__ bout,
                                                   float* __restrict__ out) {
    int g = blockIdx.x;
    int s = gstart[g], e = gstart[g + 1];
    int lane = threadIdx.x & 63;
    int wave = threadIdx.x >> 6;
    float ax = 0.f, ay = 0.f;
    for (int n = s + wave; n < e; n += 4) {
        uint v = ((const uint*)(h2b + (size_t)n * 128))[lane];
        ax += blo(v);
        ay += bhi(v);
    }
    __shared__ float2 red[4][64];
    red[wave][lane] = make_float2(ax, ay);
    __syncthreads();
    if (wave == 0) {
        float2 a = red[0][lane], b = red[1][lane], c = red[2][lane], d = red[3][lane];
        float cnt = (float)(e - s);
        float inv = (cnt > 0.f) ? (1.f / cnt) : 1.f;
        float px = (a.x + b.x + c.x + d.x) * inv;
        float py = (a.y + b.y + c.y + d.y) * inv;
        float2 w0 = ((const float2*)(Wout))[lane];
        float2 w1 = ((const float2*)(Wout + 128))[lane];
        float d0 = px * w0.x + py * w0.y;
        float d1 = px * w1.x + py * w1.y;
#pragma unroll
        for (int m = 32; m > 0; m >>= 1) {
            d0 += __shfl_xor(d0, m);
            d1 += __shfl_xor(d1, m);
        }
        if (lane == 0) {
            float l0 = d0 + bout[0];
            float l1 = d1 + bout[1];
            float mx = fmaxf(l0, l1);
            float lse = mx + logf(expf(l0 - mx) + expf(l1 - mx));
            out[g * 2 + 0] = l0 - lse;
            out[g * 2 + 1] = l1 - lse;
        }
    }
}

// ---------------- launch -----------------------------------------------------

static inline size_t alignUp(size_t x, size_t a) { return (x + a - 1) & ~(a - 1); }

extern "C" void kernel_launch(void* const* d_in, const int* in_sizes, int n_in,
                              void* d_out, int out_size, void* d_ws, size_t ws_size,
                              hipStream_t stream) {
    const float* x    = (const float*)d_in[0];
    const int*   ei   = (const int*)d_in[1];
    const int*   batch= (const int*)d_in[2];
    const float* Wl1  = (const float*)d_in[3];
    const float* bl1  = (const float*)d_in[4];
    const float* Wr1  = (const float*)d_in[5];
    const float* Wl2  = (const float*)d_in[6];
    const float* bl2  = (const float*)d_in[7];
    const float* Wr2  = (const float*)d_in[8];
    const float* Wout = (const float*)d_in[9];
    const float* bout = (const float*)d_in[10];
    float* out = (float*)d_out;

    const int N = in_sizes[0] / 64;   // 100000
    const int E = in_sizes[1] / 2;    // 1000000
    const int G = out_size / 2;       // 256

    const int* src = ei;
    const int* dst = ei + E;

    const int nScanBlocks = (N + 255) / 256;

    // workspace layout
    char* ws = (char*)d_ws;
    size_t off = 0;
    int*   deg       = (int*)(ws + off); off = alignUp(off + (size_t)N * 4, 256);
    int*   row_start = (int*)(ws + off); off = alignUp(off + (size_t)(N + 1) * 4, 256);
    int*   epos      = (int*)(ws + off); off = alignUp(off + (size_t)E * 4, 256);
    int*   csr_src   = (int*)(ws + off); off = alignUp(off + (size_t)E * 4, 256);
    int*   bsum      = (int*)(ws + off); off = alignUp(off + (size_t)512 * 4, 256);
    int*   gstart    = (int*)(ws + off); off = alignUp(off + (size_t)(G + 1) * 4, 256);
    unsigned short* xb   = (unsigned short*)(ws + off); off = alignUp(off + (size_t)N * 64 * 2, 256);
    unsigned char*  xf8  = (unsigned char*)(ws + off);  off = alignUp(off + (size_t)N * 64, 256);
    unsigned short* wbuf = (unsigned short*)(ws + off); off = alignUp(off + (size_t)49152 * 2, 256);
    unsigned short* agg1 = (unsigned short*)(ws + off); off = alignUp(off + (size_t)N * 64 * 2, 256);
    unsigned short* h1   = (unsigned short*)(ws + off); off = alignUp(off + (size_t)N * 128 * 2, 256);
    unsigned char*  h1f8 = (unsigned char*)(ws + off);  off = alignUp(off + (size_t)N * 128, 256);
    unsigned short* agg2 = (unsigned short*)(ws + off); off = alignUp(off + (size_t)N * 128 * 2, 256);
    unsigned short* h2b  = (unsigned short*)(ws + off); off = alignUp(off + (size_t)N * 128 * 2, 256);
    (void)ws_size;

    unsigned short* Wl1b = wbuf;
    unsigned short* Wr1b = wbuf + 8192;
    unsigned short* Wl2b = wbuf + 16384;
    unsigned short* Wr2b = wbuf + 32768;

    // zero deg
    hipMemsetAsync(deg, 0, (size_t)N * 4, stream);

    // phase A: count_pos + cvt_x + cvt_w + graph_bounds in one launch
    const int bCount = (E / 4 + 255) / 256;          // 977
    const int bCvtX  = (N * 64 / 8 + 255) / 256;     // 3125
    const int bCvtW  = 192;
    k_phase_a<<<bCount + bCvtX + bCvtW + 1, 256, 0, stream>>>(
        dst, deg, epos, E,
        x, xb, xf8, N * 64,
        Wl1, Wr1, Wl2, Wr2, wbuf,
        batch, gstart, N, G,
        bCount, bCvtX, bCvtW);

    // scan + placement
    k_block_sum<<<nScanBlocks, 256, 0, stream>>>(deg, bsum, N);
    k_scan_bsum<<<1, 512, 0, stream>>>(bsum, nScanBlocks);
    k_scan_final<<<nScanBlocks, 256, 0, stream>>>(deg, bsum, row_start, N);
    k_place<<<(E / 8 + 255) / 256, 256, 0, stream>>>(src, dst, row_start, epos, csr_src, E);

    // layer 1: gather (fp8) -> MFMA linear (emits h1 bf16 + h1f8 fp8)
    k_gather1<<<(N + 3) / 4, 256, 0, stream>>>(xf8, row_start, csr_src, agg1, N);
    k_linear_mfma<64, true><<<(N + 127) / 128, 256, 0, stream>>>(
        agg1, xb, Wl1b, bl1, Wr1b, h1, h1f8, N);

    // layer 2
    k_gather2<<<(N + 3) / 4, 256, 0, stream>>>(h1f8, row_start, csr_src, agg2, N);
    k_linear_mfma<128, false><<<(N + 127) / 128, 256, 0, stream>>>(
        agg2, h1, Wl2b, bl2, Wr2b, h2b, (unsigned char*)nullptr, N);

    // fused pool + head
    k_pool_head<<<G, 256, 0, stream>>>(h2b, gstart, Wout, bout, out);
}

// Round 13
// 316.246 us; speedup vs baseline: 1.4417x; 1.0004x over previous
//
#include <hip/hip_runtime.h>
#include <hip/hip_bf16.h>
#include <math.h>

typedef short short8_t __attribute__((ext_vector_type(8)));
typedef float floatx4  __attribute__((ext_vector_type(4)));
typedef float floatx2  __attribute__((ext_vector_type(2)));
typedef unsigned int uint;

// ---------------- bf16 helpers (RNE) ----------------------------------------

__device__ inline unsigned short f2b(float f) {
    uint u = __float_as_uint(f);
    u += 0x7fff + ((u >> 16) & 1);
    return (unsigned short)(u >> 16);
}
__device__ inline uint pack2(float a, float b) {
    return (uint)f2b(a) | ((uint)f2b(b) << 16);
}
__device__ inline float blo(uint v) { return __uint_as_float(v << 16); }
__device__ inline float bhi(uint v) { return __uint_as_float(v & 0xffff0000u); }

// ---------------- fp8 (e4m3) helpers ------------------------------------------

__device__ inline uint enc4_fp8(float f0, float f1, float f2, float f3) {
    uint v = __builtin_amdgcn_cvt_pk_fp8_f32(f0, f1, 0, false);
    v = __builtin_amdgcn_cvt_pk_fp8_f32(f2, f3, v, true);
    return v;
}
__device__ inline unsigned char enc1_fp8(float f) {
    return (unsigned char)(__builtin_amdgcn_cvt_pk_fp8_f32(f, f, 0, false) & 0xff);
}

// ---------------- phase A mega-kernel -----------------------------------------
// R10/R12 lessons: the atomic count pass was pinned at ~43us NOT by an atomic
// "pipe" but by cross-XCD line ping-pong (WRITE_SIZE 35MB for 4MB payload =
// a line migration every ~2 atomics). Fix: 8 histogram replicas, replica =
// blockIdx & 7 (XCD round-robin heuristic; correctness independent of the
// mapping, only locality depends on it). epos packs (rep<<24)|pos.
// Conversion work co-scheduled in the same launch rides the idle CUs.
// R11 lesson: do NOT fuse the latency-bound gather into the MFMA kernel.

__global__ __launch_bounds__(256) void k_phase_a(
    const int* __restrict__ dst, int* __restrict__ deg8, int* __restrict__ epos, int E,
    const float* __restrict__ x, unsigned short* __restrict__ xb,
    unsigned char* __restrict__ xf8, int nX,
    const float* __restrict__ Wl1, const float* __restrict__ Wr1,
    const float* __restrict__ Wl2, const float* __restrict__ Wr2,
    unsigned short* __restrict__ wbuf,
    const int* __restrict__ batch, int* __restrict__ gstart, int N, int G,
    int bCount, int bCvtX, int bCvtW) {
    int b = blockIdx.x;
    if (b < bCount) {
        int rep = b & 7;
        int* degr = deg8 + (size_t)rep * N;
        uint rtag = (uint)rep << 24;
        int e = (b * 256 + threadIdx.x) * 4;
        if (e + 3 < E) {
            int4 d4 = *(const int4*)(dst + e);
            int4 p;
            p.x = (int)(rtag | (uint)atomicAdd(&degr[d4.x], 1));
            p.y = (int)(rtag | (uint)atomicAdd(&degr[d4.y], 1));
            p.z = (int)(rtag | (uint)atomicAdd(&degr[d4.z], 1));
            p.w = (int)(rtag | (uint)atomicAdd(&degr[d4.w], 1));
            *(int4*)(epos + e) = p;
        } else {
            for (int k = e; k < E; ++k)
                epos[k] = (int)(rtag | (uint)atomicAdd(&degr[dst[k]], 1));
        }
    } else if (b < bCount + bCvtX) {
        int i = ((b - bCount) * 256 + threadIdx.x) * 8;
        if (i < nX) {
            float4 v0 = *(const float4*)(x + i);
            float4 v1 = *(const float4*)(x + i + 4);
            uint4 ob;
            ob.x = pack2(v0.x, v0.y);
            ob.y = pack2(v0.z, v0.w);
            ob.z = pack2(v1.x, v1.y);
            ob.w = pack2(v1.z, v1.w);
            *(uint4*)(xb + i) = ob;
            uint2 of;
            of.x = enc4_fp8(v0.x, v0.y, v0.z, v0.w);
            of.y = enc4_fp8(v1.x, v1.y, v1.z, v1.w);
            *(uint2*)(xf8 + i) = of;
        }
    } else if (b < bCount + bCvtX + bCvtW) {
        int i = (b - bCount - bCvtX) * 256 + threadIdx.x;
        if (i < 49152) {
            float v;
            if (i < 8192)       v = Wl1[i];
            else if (i < 16384) v = Wr1[i - 8192];
            else if (i < 32768) v = Wl2[i - 16384];
            else                v = Wr2[i - 32768];
            wbuf[i] = f2b(v);
        }
    } else {
        for (int g = threadIdx.x; g <= G; g += 256) {
            if (g == G) { gstart[G] = N; continue; }
            int lo = 0, hi = N;
            while (lo < hi) {
                int mid = (lo + hi) >> 1;
                if (batch[mid] < g) lo = mid + 1; else hi = mid;
            }
            gstart[g] = lo;
        }
    }
}

// ---------------- scan (3-phase, over 8-replica histogram) --------------------

__global__ void k_block_sum(const int* __restrict__ deg8, int* __restrict__ bsum, int n) {
    __shared__ int red[256];
    int i = blockIdx.x * 256 + threadIdx.x;
    int t = 0;
    if (i < n) {
#pragma unroll
        for (int r = 0; r < 8; ++r) t += deg8[(size_t)r * n + i];
    }
    red[threadIdx.x] = t;
    __syncthreads();
#pragma unroll
    for (int off = 128; off > 0; off >>= 1) {
        if (threadIdx.x < off) red[threadIdx.x] += red[threadIdx.x + off];
        __syncthreads();
    }
    if (threadIdx.x == 0) bsum[blockIdx.x] = red[0];
}

__global__ void k_scan_bsum(int* __restrict__ bsum, int nb) {
    __shared__ int s[512];
    int t = threadIdx.x;
    int v = (t < nb) ? bsum[t] : 0;
    s[t] = v;
    __syncthreads();
#pragma unroll
    for (int off = 1; off < 512; off <<= 1) {
        int u = (t >= off) ? s[t - off] : 0;
        __syncthreads();
        s[t] += u;
        __syncthreads();
    }
    if (t < nb) bsum[t] = s[t] - v;
}

// writes row_start (total prefix) + off8[r][node] (per-replica base)
__global__ void k_scan_final(const int* __restrict__ deg8, const int* __restrict__ bsum,
                             int* __restrict__ row_start, int* __restrict__ off8, int n) {
    __shared__ int s[256];
    int i = blockIdx.x * 256 + threadIdx.x;
    int d[8];
    int tot = 0;
    if (i < n) {
#pragma unroll
        for (int r = 0; r < 8; ++r) { d[r] = deg8[(size_t)r * n + i]; tot += d[r]; }
    }
    s[threadIdx.x] = tot;
    __syncthreads();
#pragma unroll
    for (int off = 1; off < 256; off <<= 1) {
        int u = (threadIdx.x >= off) ? s[threadIdx.x - off] : 0;
        __syncthreads();
        s[threadIdx.x] += u;
        __syncthreads();
    }
    int excl = s[threadIdx.x] - tot + bsum[blockIdx.x];
    if (i < n) {
        row_start[i] = excl;
        int run = excl;
#pragma unroll
        for (int r = 0; r < 8; ++r) { off8[(size_t)r * n + i] = run; run += d[r]; }
    }
    if (i == n - 1) row_start[n] = excl + tot;
}

// atomic-free placement, 8 edges/thread. Packed CSR (4MB, L2-resident;
// R9 lesson: strided buckets caused 16x write amplification).
__global__ void k_place(const int* __restrict__ src, const int* __restrict__ dst,
                        const int* __restrict__ off8, const int* __restrict__ epos,
                        int* __restrict__ csr_src, int E, int N) {
    int e = (blockIdx.x * blockDim.x + threadIdx.x) * 8;
    if (e + 7 < E) {
        int4 d0 = *(const int4*)(dst + e);
        int4 d1 = *(const int4*)(dst + e + 4);
        int4 p0 = *(const int4*)(epos + e);
        int4 p1 = *(const int4*)(epos + e + 4);
        int4 s0 = *(const int4*)(src + e);
        int4 s1 = *(const int4*)(src + e + 4);
        int r0 = off8[(size_t)((uint)p0.x >> 24) * N + d0.x];
        int r1 = off8[(size_t)((uint)p0.y >> 24) * N + d0.y];
        int r2 = off8[(size_t)((uint)p0.z >> 24) * N + d0.z];
        int r3 = off8[(size_t)((uint)p0.w >> 24) * N + d0.w];
        int r4 = off8[(size_t)((uint)p1.x >> 24) * N + d1.x];
        int r5 = off8[(size_t)((uint)p1.y >> 24) * N + d1.y];
        int r6 = off8[(size_t)((uint)p1.z >> 24) * N + d1.z];
        int r7 = off8[(size_t)((uint)p1.w >> 24) * N + d1.w];
        csr_src[r0 + (p0.x & 0xFFFFFF)] = s0.x;
        csr_src[r1 + (p0.y & 0xFFFFFF)] = s0.y;
        csr_src[r2 + (p0.z & 0xFFFFFF)] = s0.z;
        csr_src[r3 + (p0.w & 0xFFFFFF)] = s0.w;
        csr_src[r4 + (p1.x & 0xFFFFFF)] = s1.x;
        csr_src[r5 + (p1.y & 0xFFFFFF)] = s1.y;
        csr_src[r6 + (p1.z & 0xFFFFFF)] = s1.z;
        csr_src[r7 + (p1.w & 0xFFFFFF)] = s1.w;
    } else {
        for (int k = e; k < E; ++k) {
            int v = epos[k];
            int o = off8[(size_t)((uint)v >> 24) * N + dst[k]];
            csr_src[o + (v & 0xFFFFFF)] = src[k];
        }
    }
}

// ---------------- mean aggregation (fp8 in, bf16 out, fp32 accumulate) -------

#define ACCF8(v)                                                        \
    { floatx2 f = __builtin_amdgcn_cvt_pk_f32_fp8((v).x, false);        \
      a[0] += f[0]; a[1] += f[1];                                       \
      f = __builtin_amdgcn_cvt_pk_f32_fp8((v).x, true);                 \
      a[2] += f[0]; a[3] += f[1];                                       \
      f = __builtin_amdgcn_cvt_pk_f32_fp8((v).y, false);                \
      a[4] += f[0]; a[5] += f[1];                                       \
      f = __builtin_amdgcn_cvt_pk_f32_fp8((v).y, true);                 \
      a[6] += f[0]; a[7] += f[1]; }

// K=64: row = 64 B fp8. 8 edge-slots x 8 lanes x uint2; 2-deep unroll.
__global__ void k_gather1(const unsigned char* __restrict__ xf8,
                          const int* __restrict__ row_start,
                          const int* __restrict__ csr_src,
                          unsigned short* __restrict__ agg, int n_nodes) {
    int tid = threadIdx.x;
    int node = blockIdx.x * 4 + (tid >> 6);
    if (node >= n_nodes) return;
    int lane = tid & 63;
    int grp = lane >> 3;
    int lp  = lane & 7;
    int s = row_start[node];
    int e = row_start[node + 1];
    float a[8];
#pragma unroll
    for (int q = 0; q < 8; ++q) a[q] = 0.f;
    int i = s + grp;
    for (; i + 8 < e; i += 16) {
        int u0 = csr_src[i];
        int u1 = csr_src[i + 8];
        uint2 v0 = *(const uint2*)(xf8 + (size_t)u0 * 64 + lp * 8);
        uint2 v1 = *(const uint2*)(xf8 + (size_t)u1 * 64 + lp * 8);
        ACCF8(v0);
        ACCF8(v1);
    }
    if (i < e) {
        int u0 = csr_src[i];
        uint2 v0 = *(const uint2*)(xf8 + (size_t)u0 * 64 + lp * 8);
        ACCF8(v0);
    }
#pragma unroll
    for (int q = 0; q < 8; ++q) {
        a[q] += __shfl_xor(a[q], 8);
        a[q] += __shfl_xor(a[q], 16);
        a[q] += __shfl_xor(a[q], 32);
    }
    if (grp == 0) {
        int d = e - s;
        float scale = (d > 0) ? (1.f / (float)d) : 1.f;
        uint4 o;
        o.x = pack2(a[0] * scale, a[1] * scale);
        o.y = pack2(a[2] * scale, a[3] * scale);
        o.z = pack2(a[4] * scale, a[5] * scale);
        o.w = pack2(a[6] * scale, a[7] * scale);
        *(uint4*)(agg + (size_t)node * 64 + lp * 8) = o;
    }
}

// K=128: row = 128 B fp8. 4 edge-slots x 16 lanes x uint2; 2-deep unroll.
__global__ void k_gather2(const unsigned char* __restrict__ h1f8,
                          const int* __restrict__ row_start,
                          const int* __restrict__ csr_src,
                          unsigned short* __restrict__ agg, int n_nodes) {
    int tid = threadIdx.x;
    int node = blockIdx.x * 4 + (tid >> 6);
    if (node >= n_nodes) return;
    int lane = tid & 63;
    int grp = lane >> 4;
    int lp  = lane & 15;
    int s = row_start[node];
    int e = row_start[node + 1];
    float a[8];
#pragma unroll
    for (int q = 0; q < 8; ++q) a[q] = 0.f;
    int i = s + grp;
    for (; i + 4 < e; i += 8) {
        int u0 = csr_src[i];
        int u1 = csr_src[i + 4];
        uint2 v0 = *(const uint2*)(h1f8 + (size_t)u0 * 128 + lp * 8);
        uint2 v1 = *(const uint2*)(h1f8 + (size_t)u1 * 128 + lp * 8);
        ACCF8(v0);
        ACCF8(v1);
    }
    if (i < e) {
        int u0 = csr_src[i];
        uint2 v0 = *(const uint2*)(h1f8 + (size_t)u0 * 128 + lp * 8);
        ACCF8(v0);
    }
#pragma unroll
    for (int q = 0; q < 8; ++q) {
        a[q] += __shfl_xor(a[q], 16);
        a[q] += __shfl_xor(a[q], 32);
    }
    if (grp == 0) {
        int d = e - s;
        float scale = (d > 0) ? (1.f / (float)d) : 1.f;
        uint4 o;
        o.x = pack2(a[0] * scale, a[1] * scale);
        o.y = pack2(a[2] * scale, a[3] * scale);
        o.z = pack2(a[4] * scale, a[5] * scale);
        o.w = pack2(a[6] * scale, a[7] * scale);
        *(uint4*)(agg + (size_t)node * 128 + lp * 8) = o;
    }
}

// ---------------- MFMA SAGE linear: out = relu(agg@Wl.T + bl + xin@Wr.T) ----
// F8OUT: epilogue also emits fp8 copy (next layer's gather operand).

template <int K, bool F8OUT>
__global__ __launch_bounds__(256) void k_linear_mfma(
    const unsigned short* __restrict__ aggA, const unsigned short* __restrict__ xinA,
    const unsigned short* __restrict__ Wlb,  const float* __restrict__ bl,
    const unsigned short* __restrict__ Wrb,  unsigned short* __restrict__ out,
    unsigned char* __restrict__ outf8, int n_nodes) {
    constexpr int NCH = (2 * K) / 32;
    __shared__ __align__(16) short As[128 * 32];   // 8 KB

    int tid  = threadIdx.x;
    int lane = tid & 63;
    int wave = tid >> 6;
    int quad = lane >> 4;
    int lr   = lane & 15;
    int node0 = blockIdx.x * 128;

    floatx4 acc[8][2];
#pragma unroll
    for (int mi = 0; mi < 8; ++mi)
#pragma unroll
        for (int ni = 0; ni < 2; ++ni)
            acc[mi][ni] = (floatx4){0.f, 0.f, 0.f, 0.f};

    int srow = tid >> 2;
    int sslot = tid & 3;

#pragma unroll
    for (int c = 0; c < NCH; ++c) {
        const unsigned short* srcA;
        const unsigned short* srcW;
        int kb;
        if (c < K / 32) { srcA = aggA; srcW = Wlb; kb = c * 32; }
        else            { srcA = xinA; srcW = Wrb; kb = c * 32 - K; }

        __syncthreads();
        {
            int n1 = node0 + srow;       if (n1 >= n_nodes) n1 = n_nodes - 1;
            int n2 = node0 + srow + 64;  if (n2 >= n_nodes) n2 = n_nodes - 1;
            uint4 v1 = *(const uint4*)(srcA + (size_t)n1 * K + kb + sslot * 8);
            uint4 v2 = *(const uint4*)(srcA + (size_t)n2 * K + kb + sslot * 8);
            *(uint4*)(&As[srow * 32 + sslot * 8]) = v1;
            *(uint4*)(&As[(srow + 64) * 32 + sslot * 8]) = v2;
        }
        __syncthreads();

        short8_t bfrag[2];
#pragma unroll
        for (int ni = 0; ni < 2; ++ni) {
            int j = wave * 32 + ni * 16 + lr;
            bfrag[ni] = *(const short8_t*)(srcW + (size_t)j * K + kb + quad * 8);
        }
#pragma unroll
        for (int mi = 0; mi < 8; ++mi) {
            short8_t af = *(const short8_t*)(&As[(mi * 16 + lr) * 32 + quad * 8]);
            acc[mi][0] = __builtin_amdgcn_mfma_f32_16x16x32_bf16(af, bfrag[0], acc[mi][0], 0, 0, 0);
            acc[mi][1] = __builtin_amdgcn_mfma_f32_16x16x32_bf16(af, bfrag[1], acc[mi][1], 0, 0, 0);
        }
    }

    float b0 = bl[wave * 32 + lr];
    float b1 = bl[wave * 32 + 16 + lr];
    int j0 = wave * 32 + lr;
#pragma unroll
    for (int mi = 0; mi < 8; ++mi) {
#pragma unroll
        for (int r = 0; r < 4; ++r) {
            int node = node0 + mi * 16 + quad * 4 + r;
            if (node < n_nodes) {
                float v0 = fmaxf(acc[mi][0][r] + b0, 0.f);
                float v1 = fmaxf(acc[mi][1][r] + b1, 0.f);
                out[(size_t)node * 128 + j0]      = f2b(v0);
                out[(size_t)node * 128 + j0 + 16] = f2b(v1);
                if (F8OUT) {
                    outf8[(size_t)node * 128 + j0]      = enc1_fp8(v0);
                    outf8[(size_t)node * 128 + j0 + 16] = enc1_fp8(v1);
                }
            }
        }
    }
}

// ---------------- fused pool + head -------------------------------------------

__global__ __launch_bounds__(256) void k_pool_head(const unsigned short* __restrict__ h2b,
                                                   const int* __restrict__ gstart,
                                                   const float* __restrict__ Wout,
                                                   const float* __restrict__ bout,
                                                   float* __restrict__ out) {
    int g = blockIdx.x;
    int s = gstart[g], e = gstart[g + 1];
    int lane = threadIdx.x & 63;
    int wave = threadIdx.x >> 6;
    float ax = 0.f, ay = 0.f;
    for (int n = s + wave; n < e; n += 4) {
        uint v = ((const uint*)(h2b + (size_t)n * 128))[lane];
        ax += blo(v);
        ay += bhi(v);
    }
    __shared__ float2 red[4][64];
    red[wave][lane] = make_float2(ax, ay);
    __syncthreads();
    if (wave == 0) {
        float2 a = red[0][lane], b = red[1][lane], c = red[2][lane], d = red[3][lane];
        float cnt = (float)(e - s);
        float inv = (cnt > 0.f) ? (1.f / cnt) : 1.f;
        float px = (a.x + b.x + c.x + d.x) * inv;
        float py = (a.y + b.y + c.y + d.y) * inv;
        float2 w0 = ((const float2*)(Wout))[lane];
        float2 w1 = ((const float2*)(Wout + 128))[lane];
        float d0 = px * w0.x + py * w0.y;
        float d1 = px * w1.x + py * w1.y;
#pragma unroll
        for (int m = 32; m > 0; m >>= 1) {
            d0 += __shfl_xor(d0, m);
            d1 += __shfl_xor(d1, m);
        }
        if (lane == 0) {
            float l0 = d0 + bout[0];
            float l1 = d1 + bout[1];
            float mx = fmaxf(l0, l1);
            float lse = mx + logf(expf(l0 - mx) + expf(l1 - mx));
            out[g * 2 + 0] = l0 - lse;
            out[g * 2 + 1] = l1 - lse;
        }
    }
}

// ---------------- launch -----------------------------------------------------

static inline size_t alignUp(size_t x, size_t a) { return (x + a - 1) & ~(a - 1); }

extern "C" void kernel_launch(void* const* d_in, const int* in_sizes, int n_in,
                              void* d_out, int out_size, void* d_ws, size_t ws_size,
                              hipStream_t stream) {
    const float* x    = (const float*)d_in[0];
    const int*   ei   = (const int*)d_in[1];
    const int*   batch= (const int*)d_in[2];
    const float* Wl1  = (const float*)d_in[3];
    const float* bl1  = (const float*)d_in[4];
    const float* Wr1  = (const float*)d_in[5];
    const float* Wl2  = (const float*)d_in[6];
    const float* bl2  = (const float*)d_in[7];
    const float* Wr2  = (const float*)d_in[8];
    const float* Wout = (const float*)d_in[9];
    const float* bout = (const float*)d_in[10];
    float* out = (float*)d_out;

    const int N = in_sizes[0] / 64;   // 100000
    const int E = in_sizes[1] / 2;    // 1000000
    const int G = out_size / 2;       // 256

    const int* src = ei;
    const int* dst = ei + E;

    const int nScanBlocks = (N + 255) / 256;

    // workspace layout
    char* ws = (char*)d_ws;
    size_t off = 0;
    int*   deg8      = (int*)(ws + off); off = alignUp(off + (size_t)8 * N * 4, 256);
    int*   off8      = (int*)(ws + off); off = alignUp(off + (size_t)8 * N * 4, 256);
    int*   row_start = (int*)(ws + off); off = alignUp(off + (size_t)(N + 1) * 4, 256);
    int*   epos      = (int*)(ws + off); off = alignUp(off + (size_t)E * 4, 256);
    int*   csr_src   = (int*)(ws + off); off = alignUp(off + (size_t)E * 4, 256);
    int*   bsum      = (int*)(ws + off); off = alignUp(off + (size_t)512 * 4, 256);
    int*   gstart    = (int*)(ws + off); off = alignUp(off + (size_t)(G + 1) * 4, 256);
    unsigned short* xb   = (unsigned short*)(ws + off); off = alignUp(off + (size_t)N * 64 * 2, 256);
    unsigned char*  xf8  = (unsigned char*)(ws + off);  off = alignUp(off + (size_t)N * 64, 256);
    unsigned short* wbuf = (unsigned short*)(ws + off); off = alignUp(off + (size_t)49152 * 2, 256);
    unsigned short* agg1 = (unsigned short*)(ws + off); off = alignUp(off + (size_t)N * 64 * 2, 256);
    unsigned short* h1   = (unsigned short*)(ws + off); off = alignUp(off + (size_t)N * 128 * 2, 256);
    unsigned char*  h1f8 = (unsigned char*)(ws + off);  off = alignUp(off + (size_t)N * 128, 256);
    unsigned short* agg2 = (unsigned short*)(ws + off); off = alignUp(off + (size_t)N * 128 * 2, 256);
    unsigned short* h2b  = (unsigned short*)(ws + off); off = alignUp(off + (size_t)N * 128 * 2, 256);
    (void)ws_size;

    unsigned short* Wl1b = wbuf;
    unsigned short* Wr1b = wbuf + 8192;
    unsigned short* Wl2b = wbuf + 16384;
    unsigned short* Wr2b = wbuf + 32768;

    // zero the 8-replica histogram
    hipMemsetAsync(deg8, 0, (size_t)8 * N * 4, stream);

    // phase A: replicated count + cvt_x + cvt_w + graph_bounds in one launch
    const int bCount = (E / 4 + 255) / 256;          // 977
    const int bCvtX  = (N * 64 / 8 + 255) / 256;     // 3125
    const int bCvtW  = 192;
    k_phase_a<<<bCount + bCvtX + bCvtW + 1, 256, 0, stream>>>(
        dst, deg8, epos, E,
        x, xb, xf8, N * 64,
        Wl1, Wr1, Wl2, Wr2, wbuf,
        batch, gstart, N, G,
        bCount, bCvtX, bCvtW);

    // scan (8-replica) + placement
    k_block_sum<<<nScanBlocks, 256, 0, stream>>>(deg8, bsum, N);
    k_scan_bsum<<<1, 512, 0, stream>>>(bsum, nScanBlocks);
    k_scan_final<<<nScanBlocks, 256, 0, stream>>>(deg8, bsum, row_start, off8, N);
    k_place<<<(E / 8 + 255) / 256, 256, 0, stream>>>(src, dst, off8, epos, csr_src, E, N);

    // layer 1: gather (fp8) -> MFMA linear (emits h1 bf16 + h1f8 fp8)
    k_gather1<<<(N + 3) / 4, 256, 0, stream>>>(xf8, row_start, csr_src, agg1, N);
    k_linear_mfma<64, true><<<(N + 127) / 128, 256, 0, stream>>>(
        agg1, xb, Wl1b, bl1, Wr1b, h1, h1f8, N);

    // layer 2
    k_gather2<<<(N + 3) / 4, 256, 0, stream>>>(h1f8, row_start, csr_src, agg2, N);
    k_linear_mfma<128, false><<<(N + 127) / 128, 256, 0, stream>>>(
        agg2, h1, Wl2b, bl2, Wr2b, h2b, (unsigned char*)nullptr, N);

    // fused pool + head
    k_pool_head<<<G, 256, 0, stream>>>(h2b, gstart, Wout, bout, out);
}